// Round 9
// baseline (158.108 us; speedup 1.0000x reference)
//
#include <hip/hip_runtime.h>
#include <math.h>

#define BB 8
#define DD 768
#define HWN 1024
#define NS 256
#define PPAD 3072
#define O1 256
#define O2 128

typedef __attribute__((ext_vector_type(8))) short bf16x8;
typedef __attribute__((ext_vector_type(4))) float f32x4;

__constant__ int c_du[12] = {1,-1,0,0,2,-2,0,0,1, 1,-1,-1};
__constant__ int c_dv[12] = {0, 0,1,-1,0, 0,2,-2,1,-1, 1,-1};
__constant__ signed char c_rk[25] = {
  -1,-1, 5,-1,-1,
  -1,11, 1,10,-1,
   7, 3,-1, 2, 6,
  -1, 9, 0, 8,-1,
  -1,-1, 4,-1,-1};

__device__ inline ushort f2bf(float x) {
  unsigned u = __float_as_uint(x);
  u += 0x7FFF + ((u >> 16) & 1);
  return (ushort)(u >> 16);
}
__device__ inline float bf2f(ushort h) { return __uint_as_float(((unsigned)h) << 16); }

__device__ inline bool row_sampled(int row) {
  return ((row | (row >> 5)) & 1) == 0;
}

// ============ K1: pool(6144) | EH(512) | transpose(208) | identity fill(2048x8rows) ============
__global__ void __launch_bounds__(256) k1(const float* __restrict__ feat,
    const float* __restrict__ cemb, const float* __restrict__ W1,
    const float* __restrict__ b1, const float* __restrict__ W2,
    float* __restrict__ fg, ushort* __restrict__ g16,
    float* __restrict__ EH, ushort* __restrict__ WT16, ushort* __restrict__ W2T16,
    float* __restrict__ A, int* __restrict__ done) {
  __shared__ __align__(16) float sm[64 * 65];
  int blk = blockIdx.x;
  int t = threadIdx.x;
  if (blk < 6144) {
    // ---- pool + site gather ----
    int row = blk;
    const float4 v = reinterpret_cast<const float4*>(feat + (size_t)row * HWN)[t];
    float s = v.x + v.y + v.z + v.w;
#pragma unroll
    for (int m = 32; m >= 1; m >>= 1) s += __shfl_xor(s, m, 64);
    if ((t & 63) == 0) sm[t >> 6] = s;
    if ((t & 8) == 0) {
      int b = row / DD, d = row - b * DD;
      int u = t >> 4, r = t & 7;
      int s1 = u * 16 + 2 * r;
      g16[((size_t)(b * NS + s1)) * DD + d] = f2bf(v.x);
      g16[((size_t)(b * NS + s1 + 1)) * DD + d] = f2bf(v.z);
    }
    __syncthreads();
    if (t == 0) fg[row] = (sm[0] + sm[1] + sm[2] + sm[3]) * (1.0f / 1024.0f);
  } else if (blk < 6656) {
    // ---- EH ----
    int bs = blk - 6144;
    int c = bs >> 8, s = bs & 255;
    int u = s >> 4, v = s & 15;
    int pix = (u << 6) + (v << 1);
    float* ce = sm;
    if (t < 128) ce[t] = cemb[(size_t)pix * 128 + t];
    __syncthreads();
    const float* W = W1 + ((size_t)c * 1664 + 1536) * O1;
    float acc = 0.f;
    for (int e = 0; e < 128; e++) acc = fmaf(ce[e], W[(size_t)e * O1 + t], acc);
    EH[((size_t)(c * NS + s)) * O1 + t] = 0.5f * (acc + b1[c * O1 + t]);
  } else if (blk < 6864) {
    // ---- transpose ----
    int r0 = blk - 6656;
    const float* src; ushort* dst; int K, N, k0, n0;
    if (r0 < 192) {
      int ch = r0 / 48, r = r0 % 48;
      int c = ch & 1, half = ch >> 1;
      src = W1 + ((size_t)c * 1664 + half * 768) * 256;
      dst = WT16 + (size_t)ch * 256 * 768;
      K = 768; N = 256; k0 = (r >> 2) * 64; n0 = (r & 3) * 64;
    } else {
      int r = r0 - 192;
      int c = r >> 3; int q = r & 7;
      src = W2 + (size_t)c * 256 * 128;
      dst = W2T16 + (size_t)c * 128 * 256;
      K = 256; N = 128; k0 = (q >> 1) * 64; n0 = (q & 1) * 64;
    }
    float (*T)[65] = reinterpret_cast<float(*)[65]>(sm);
    for (int i = 0; i < 16; i++) {
      int idx = i * 256 + t; int kl = idx >> 6, nl = idx & 63;
      T[kl][nl] = src[(size_t)(k0 + kl) * N + n0 + nl];
    }
    __syncthreads();
    for (int i = 0; i < 16; i++) {
      int idx = i * 256 + t; int nl = idx >> 6, kl = idx & 63;
      dst[(size_t)(n0 + nl) * K + k0 + kl] = f2bf(T[kl][nl]);
    }
  } else {
    // ---- identity fill: 8 global rows per block, non-sampled only ----
    if (blk == 6864 && t < 16) {
      __hip_atomic_store(&done[t], 0, __ATOMIC_RELAXED, __HIP_MEMORY_SCOPE_AGENT);
    }
    int r0 = (blk - 6864) * 8;
#pragma unroll
    for (int i = 0; i < 8; i++) {
      int r_g = r0 + i;
      int row = r_g & 1023;
      if (!row_sampled(row)) {
        float4 o = make_float4(0.f, 0.f, 0.f, 0.f);
        if ((row >> 2) == t) {
          float dv = 1.0f / (1.0f + 1e-8f);
          int e = row & 3;
          if (e == 0) o.x = dv; else if (e == 1) o.y = dv;
          else if (e == 2) o.z = dv; else o.w = dv;
        }
        reinterpret_cast<float4*>(A + (size_t)r_g * 1024)[t] = o;
      }
    }
  }
}

// ============ K2: gemm_mfma(512) | zpart(96) ============
__global__ void __launch_bounds__(256) k2(const ushort* __restrict__ g16,
    const ushort* __restrict__ WT16, const float* __restrict__ EHb,
    const float* __restrict__ fg, const float* __restrict__ muW1,
    const float* __restrict__ lsW1,
    ushort* __restrict__ Fb16, float* __restrict__ zscr) {
  __shared__ __align__(16) float sm[4096];
  int blk = blockIdx.x;
  int t = threadIdx.x;
  if (blk < 512) {
    int mt = blk & 31, nt = (blk >> 5) & 3, ch = blk >> 7;
    int c = ch & 1;
    int row0 = mt * 64, col0 = nt * 64;
    int wid = t >> 6, l = t & 63;
    int wm = wid & 1, wn = wid >> 1;
    int lm = l & 15, lk = (l >> 4) * 8;
    float (*ehs)[64] = reinterpret_cast<float(*)[64]>(sm);
    int s0 = row0 & 255;
    for (int i = 0; i < 16; i++) {
      int idx = i * 256 + t; int rl = idx >> 6, nl = idx & 63;
      ehs[rl][nl] = EHb[((size_t)(c * 256 + s0 + rl)) * 256 + col0 + nl];
    }
    f32x4 acc[2][2] = {};
    const ushort* ap0 = g16 + (size_t)(row0 + wm * 32 + lm) * DD + lk;
    const ushort* bp0 = WT16 + ((size_t)ch * 256 + col0 + wn * 32 + lm) * DD + lk;
#pragma unroll 4
    for (int k0 = 0; k0 < DD; k0 += 32) {
      bf16x8 a0 = *(const bf16x8*)(ap0 + k0);
      bf16x8 a1 = *(const bf16x8*)(ap0 + 16 * DD + k0);
      bf16x8 b0 = *(const bf16x8*)(bp0 + k0);
      bf16x8 b1 = *(const bf16x8*)(bp0 + 16 * DD + k0);
      acc[0][0] = __builtin_amdgcn_mfma_f32_16x16x32_bf16(a0, b0, acc[0][0], 0, 0, 0);
      acc[0][1] = __builtin_amdgcn_mfma_f32_16x16x32_bf16(a0, b1, acc[0][1], 0, 0, 0);
      acc[1][0] = __builtin_amdgcn_mfma_f32_16x16x32_bf16(a1, b0, acc[1][0], 0, 0, 0);
      acc[1][1] = __builtin_amdgcn_mfma_f32_16x16x32_bf16(a1, b1, acc[1][1], 0, 0, 0);
    }
    __syncthreads();
#pragma unroll
    for (int i = 0; i < 2; i++)
#pragma unroll
      for (int jj = 0; jj < 2; jj++)
#pragma unroll
        for (int r = 0; r < 4; r++) {
          int rm = wm * 32 + i * 16 + (l >> 4) * 4 + r;
          int cn = wn * 32 + jj * 16 + lm;
          float vo = acc[i][jj][r] + ehs[rm][cn];
          Fb16[((size_t)ch * 2048 + row0 + rm) * 256 + col0 + cn] = f2bf(vo);
        }
  } else {
    int i = blk - 512;
    int chunk = i % 6, path = (i / 6) & 1, b = i / 12;
    int rg = t >> 6, ct = t & 63;
    float* sf = sm;
    float (*red)[256] = reinterpret_cast<float(*)[256]>(sm + 128);
    if (t < 128) sf[t] = fg[b * DD + chunk * 128 + t];
    __syncthreads();
    const float* W = (path ? lsW1 : muW1) + (size_t)(chunk * 128) * 256;
    float acc[4] = {0.f, 0.f, 0.f, 0.f};
#pragma unroll 4
    for (int it = 0; it < 32; it++) {
      int d = it * 4 + rg;
      float f = sf[d];
      float4 w = *reinterpret_cast<const float4*>(W + (size_t)d * 256 + ct * 4);
      acc[0] = fmaf(f, w.x, acc[0]);
      acc[1] = fmaf(f, w.y, acc[1]);
      acc[2] = fmaf(f, w.z, acc[2]);
      acc[3] = fmaf(f, w.w, acc[3]);
    }
    *reinterpret_cast<float4*>(&red[rg][ct * 4]) =
        make_float4(acc[0], acc[1], acc[2], acc[3]);
    __syncthreads();
    zscr[(((size_t)(b * 2 + path)) * 6 + chunk) * 256 + t] =
        red[0][t] + red[1][t] + red[2][t] + red[3][t];
  }
}

// ============ K3: pairmlp(832)+A rows+publish | zfinish(832..839) | diffuse(840..855) ============
__global__ void __launch_bounds__(256) k3(const ushort* __restrict__ Fb16,
    const ushort* __restrict__ W2T16, const float* __restrict__ b2,
    const float* __restrict__ W3, const float* __restrict__ b3,
    const float* __restrict__ zscr,
    const float* __restrict__ mub1, const float* __restrict__ muW2,
    const float* __restrict__ mub2,
    const float* __restrict__ lsb1, const float* __restrict__ lsW2,
    const float* __restrict__ lsb2, const float* __restrict__ eps,
    float* __restrict__ val,
    float* __restrict__ o_zmu, float* __restrict__ o_zls, float* __restrict__ o_zs,
    float* __restrict__ A, int* __restrict__ done,
    const float* __restrict__ cam,
    const float* __restrict__ csc, const float* __restrict__ cbi,
    float* __restrict__ o_cam, float* __restrict__ o_conf) {
  __shared__ __align__(16) ushort h1s[64 * 256];
  __shared__ float psum2[2][64];
  __shared__ float sval[64];
  __shared__ float sinv[8];
  int blk = blockIdx.x;
  int t = threadIdx.x;
  if (blk < 832) {
    // ---- pairmlp: grp covers 5 whole sites (60 real pairs, 4 dummies) ----
    int bc = blk / 52, grp = blk - bc * 52;
    int b = bc >> 1, c = bc & 1;
    int site0 = grp * 5;
    int nsit = (site0 + 5 <= 256) ? 5 : (256 - site0);
    int npairs = nsit * 12;
    int wid = t >> 6, l = t & 63;
    int wm = wid & 1, wn = wid >> 1;
    int lm = l & 15, lk = (l >> 4) * 8;
    {
      int p_l = t >> 2, q = t & 3;
      int sl = p_l / 12, ko = p_l - sl * 12;
      bool realp = p_l < npairs;
      int s = site0 + (realp ? sl : 0);
      int u = s >> 4, v = s & 15;
      int ub = u + c_du[ko], vb = v + c_dv[ko];
      bool vld = realp && (ub >= 0) && (ub < 16) && (vb >= 0) && (vb < 16);
      int sb = vld ? ub * 16 + vb : s;
      const ushort* f1p = Fb16 + ((size_t)(c * 2048 + b * 256 + s)) * 256 + q * 64;
      const ushort* f2p = Fb16 + ((size_t)((2 + c) * 2048 + b * 256 + sb)) * 256 + q * 64;
      char* hb = (char*)h1s;
#pragma unroll
      for (int kk = 0; kk < 64; kk += 8) {
        bf16x8 x1 = *(const bf16x8*)(f1p + kk);
        bf16x8 x2 = *(const bf16x8*)(f2p + kk);
        bf16x8 o;
#pragma unroll
        for (int e = 0; e < 8; e++) {
          float a = bf2f((ushort)x1[e]) + bf2f((ushort)x2[e]);
          o[e] = (short)f2bf(fmaxf(a, 0.f));
        }
        int byt = (p_l * 512 + (q * 64 + kk) * 2) ^ ((p_l & 7) << 4);
        *(bf16x8*)(hb + byt) = o;
      }
    }
    __syncthreads();
    f32x4 acc[2][4] = {};
    const ushort* wp = W2T16 + ((size_t)(c * 128 + wn * 64 + lm)) * 256 + lk;
    const char* hb = (const char*)h1s;
    int p0 = wm * 32 + lm;
    int swz = (p0 & 7) << 4;
#pragma unroll 2
    for (int k0 = 0; k0 < 256; k0 += 32) {
      bf16x8 a0 = *(const bf16x8*)(hb + ((p0 * 512 + (k0 + lk) * 2) ^ swz));
      bf16x8 a1 = *(const bf16x8*)(hb + (((p0 + 16) * 512 + (k0 + lk) * 2) ^ swz));
#pragma unroll
      for (int nf = 0; nf < 4; nf++) {
        bf16x8 bb = *(const bf16x8*)(wp + nf * 16 * 256 + k0);
        acc[0][nf] = __builtin_amdgcn_mfma_f32_16x16x32_bf16(a0, bb, acc[0][nf], 0, 0, 0);
        acc[1][nf] = __builtin_amdgcn_mfma_f32_16x16x32_bf16(a1, bb, acc[1][nf], 0, 0, 0);
      }
    }
    float b2v[4], w3v[4];
#pragma unroll
    for (int nf = 0; nf < 4; nf++) {
      int col = wn * 64 + nf * 16 + lm;
      b2v[nf] = b2[c * 128 + col];
      w3v[nf] = W3[c * 128 + col];
    }
    float part[2][4];
#pragma unroll
    for (int mf = 0; mf < 2; mf++)
#pragma unroll
      for (int r = 0; r < 4; r++) {
        float ssum = 0.f;
#pragma unroll
        for (int nf = 0; nf < 4; nf++) {
          float h = fmaxf(acc[mf][nf][r] + b2v[nf], 0.f);
          ssum = fmaf(h, w3v[nf], ssum);
        }
        part[mf][r] = ssum;
      }
#pragma unroll
    for (int m = 1; m <= 8; m <<= 1)
#pragma unroll
      for (int mf = 0; mf < 2; mf++)
#pragma unroll
        for (int r = 0; r < 4; r++)
          part[mf][r] += __shfl_xor(part[mf][r], m, 64);
    if (lm == 0) {
#pragma unroll
      for (int mf = 0; mf < 2; mf++)
#pragma unroll
        for (int r = 0; r < 4; r++)
          psum2[wn][wm * 32 + mf * 16 + (l >> 4) * 4 + r] = part[mf][r];
    }
    __syncthreads();
    if (t < 64) {
      int pl = t;
      int sl2 = pl / 12, ko2 = pl - sl2 * 12;
      bool realp2 = pl < npairs;
      int ss = site0 + (realp2 ? sl2 : 0);
      int uu = ss >> 4, vv2 = ss & 15;
      int ub2 = uu + c_du[ko2], vb2 = vv2 + c_dv[ko2];
      bool vld2 = realp2 && (ub2 >= 0) && (ub2 < 16) && (vb2 >= 0) && (vb2 < 16);
      float lg = psum2[0][t] + psum2[1][t] + b3[c];
      float sv = 1.0f / (1.0f + expf(-lg));
      float outv = vld2 ? sv : 0.0f;
      sval[t] = outv;
      if (realp2) {
        // device-scope store so the diffuse consumer (possibly another XCD) sees it
        __hip_atomic_store(&val[(size_t)bc * PPAD + site0 * 12 + pl], outv,
                           __ATOMIC_RELAXED, __HIP_MEMORY_SCOPE_AGENT);
      }
    }
    __syncthreads();
    if (t < nsit) {
      float ssum = 1.f;
#pragma unroll
      for (int k = 0; k < 12; k++) ssum += sval[t * 12 + k];
      sinv[t] = 1.f / (ssum + 1e-8f);
    }
    __syncthreads();
    for (int sl3 = 0; sl3 < nsit; sl3++) {
      int ss = site0 + sl3;
      int uu = ss >> 4, vv = ss & 15;
      int row = uu * 64 + 2 * vv;
      size_t base = (size_t)bc * HWN * HWN + (size_t)row * HWN;
      float inv = sinv[sl3];
      float vo[4];
#pragma unroll
      for (int e = 0; e < 4; e++) {
        int col = t * 4 + e;
        float x = 0.f;
        if (col == row) {
          x = inv;
        } else if ((col & 33) == 0) {
          int cu = col >> 6, cv = (col & 31) >> 1;
          int du = cu - uu + 2, dv = cv - vv + 2;
          if (((unsigned)du < 5u) && ((unsigned)dv < 5u)) {
            int k = c_rk[du * 5 + dv];
            if (k >= 0) x = sval[sl3 * 12 + k] * inv;
          }
        }
        vo[e] = x;
      }
      reinterpret_cast<float4*>(A + base)[t] =
          make_float4(vo[0], vo[1], vo[2], vo[3]);
    }
    __syncthreads();
    __threadfence();
    if (t == 0) {
      __hip_atomic_fetch_add(&done[bc], 1, __ATOMIC_RELEASE, __HIP_MEMORY_SCOPE_AGENT);
    }
  } else if (blk < 840) {
    // ---- zfinish ----
    int b = blk - 832;
    float* shm = (float*)h1s;
    float* shl = shm + 256;
    float* zres = shm + 512;
    float hm = mub1[t], hl = lsb1[t];
#pragma unroll
    for (int ch = 0; ch < 6; ch++) {
      hm += zscr[(((size_t)(b * 2 + 0)) * 6 + ch) * 256 + t];
      hl += zscr[(((size_t)(b * 2 + 1)) * 6 + ch) * 256 + t];
    }
    shm[t] = fmaxf(hm, 0.f);
    shl[t] = fmaxf(hl, 0.f);
    __syncthreads();
    if (t < 128 && (t & 63) < 8) {
      int path = t >> 6, kk = t & 7;
      const float* W2p = path ? lsW2 : muW2;
      const float* bi = path ? lsb2 : mub2;
      const float* sh = path ? shl : shm;
      float z = bi[kk];
      for (int i = 0; i < 256; i++) z = fmaf(sh[i], W2p[i * 8 + kk], z);
      zres[path * 8 + kk] = z;
    }
    __syncthreads();
    if (t < 8) {
      float zm = zres[t], zl = zres[8 + t];
      o_zmu[b * 8 + t] = zm;
      o_zls[b * 8 + t] = zl;
      o_zs[b * 8 + t] = zm + expf(zl) * eps[b * 8 + t];
    }
  } else {
    // ---- diffuse: wait for this bc's 52 producer blocks, then run ----
    int bc = blk - 840;
    float* M = (float*)h1s;
    if (t == 0) {
      while (__hip_atomic_load(&done[bc], __ATOMIC_ACQUIRE,
                               __HIP_MEMORY_SCOPE_AGENT) != 52) {
        __builtin_amdgcn_s_sleep(16);
      }
    }
    __syncthreads();
    __threadfence();
    int u = t >> 4, v = t & 15;
    int pix = (u << 6) + (v << 1);
    const float* camr = cam + (size_t)bc * HWN;
    float m = camr[pix];
    float vv[12];
    int nb[12];
    float ssum = 1.f;
#pragma unroll
    for (int k = 0; k < 12; k++) {
      int ub = u + c_du[k], vb = v + c_dv[k];
      bool vld = (ub >= 0) && (ub < 16) && (vb >= 0) && (vb < 16);
      nb[k] = vld ? ub * 16 + vb : t;
      vv[k] = vld ? __hip_atomic_load(&val[(size_t)bc * PPAD + t * 12 + k],
                                      __ATOMIC_RELAXED, __HIP_MEMORY_SCOPE_AGENT)
                  : 0.0f;
      ssum += vv[k];
    }
    float inv = 1.0f / (ssum + 1e-8f);
    float degn = ssum * inv;
    M[t] = m;
    __syncthreads();
    for (int step = 0; step < 3; step++) {
      float accv = m;
#pragma unroll
      for (int k = 0; k < 12; k++) accv = fmaf(vv[k], M[nb[k]], accv);
      float L = accv * inv - degn * m;
      m = fmaf(0.1f, L, m);
      __syncthreads();
      M[t] = m;
      __syncthreads();
    }
    float scale = csc[0], bias = cbi[0];
    for (int p = t; p < HWN; p += 256) {
      int ppi = p >> 5, ppj = p & 31;
      float x;
      if (((ppi | ppj) & 1) == 0) x = M[(ppi >> 1) * 16 + (ppj >> 1)];
      else x = camr[p];
      x = fminf(fmaxf(x, 0.0f), 1.0f);
      o_cam[(size_t)bc * HWN + p] = x;
      o_conf[(size_t)bc * HWN + p] = 1.0f / (1.0f + expf(-(scale * x + bias)));
    }
  }
}

extern "C" void kernel_launch(void* const* d_in, const int* in_sizes, int n_in,
                              void* d_out, int out_size, void* d_ws, size_t ws_size,
                              hipStream_t stream) {
  const float* feat = (const float*)d_in[0];
  const float* cam  = (const float*)d_in[1];
  const float* eps  = (const float*)d_in[3];
  const float* cemb = (const float*)d_in[4];
  const float* aW1  = (const float*)d_in[5];
  const float* ab1  = (const float*)d_in[6];
  const float* aW2  = (const float*)d_in[7];
  const float* ab2  = (const float*)d_in[8];
  const float* aW3  = (const float*)d_in[9];
  const float* ab3  = (const float*)d_in[10];
  const float* muW1 = (const float*)d_in[11];
  const float* mub1 = (const float*)d_in[12];
  const float* muW2 = (const float*)d_in[13];
  const float* mub2 = (const float*)d_in[14];
  const float* lsW1 = (const float*)d_in[15];
  const float* lsb1 = (const float*)d_in[16];
  const float* lsW2 = (const float*)d_in[17];
  const float* lsb2 = (const float*)d_in[18];
  const float* csc  = (const float*)d_in[19];
  const float* cbi  = (const float*)d_in[20];

  float* out = (float*)d_out;
  float* o_cam  = out;                       // 16384
  float* o_zmu  = out + 16384;               // 64
  float* o_zls  = out + 16448;               // 64
  float* o_zs   = out + 16512;               // 64
  float* o_A    = out + 16576;               // 16777216
  float* o_conf = out + 16793792;            // 16384

  // ALL scratch in d_ws
  float*  ws    = (float*)d_ws;
  float*  valb  = ws;                        // [0, 49152)
  float*  fg    = ws + 49152;                // [49152, 55296)
  float*  EHb   = ws + 55296;                // [55296, 186368)
  float*  zscr  = ws + 186368;               // [186368, 210944)
  ushort* g16   = (ushort*)(ws + 210944);    // 2048*768 bf16
  ushort* WT16  = (ushort*)(ws + 997376);    // 4*256*768 bf16
  ushort* W2T16 = (ushort*)(ws + 1390592);   // 2*128*256 bf16
  ushort* Fb16  = (ushort*)(ws + 1423360);   // 4*2048*256 bf16 (ends 2471936)
  int*    done  = (int*)(ws + 2480000);      // 16 ints, zeroed by k1

  hipLaunchKernelGGL(k1, dim3(6864 + 2048), dim3(256), 0, stream,
                     feat, cemb, aW1, ab1, aW2, fg, g16, EHb, WT16, W2T16, o_A, done);
  hipLaunchKernelGGL(k2, dim3(608), dim3(256), 0, stream,
                     g16, WT16, EHb, fg, muW1, lsW1, Fb16, zscr);
  hipLaunchKernelGGL(k3, dim3(856), dim3(256), 0, stream,
                     Fb16, W2T16, ab2, aW3, ab3, zscr,
                     mub1, muW2, mub2, lsb1, lsW2, lsb2, eps,
                     valb, o_zmu, o_zls, o_zs, o_A, done,
                     cam, csc, cbi, o_cam, o_conf);
}

// Round 10
// 84.102 us; speedup vs baseline: 1.8800x; 1.8800x over previous
//
#include <hip/hip_runtime.h>
#include <math.h>

#define BB 8
#define DD 768
#define HWN 1024
#define NS 256
#define PPAD 3072
#define O1 256
#define O2 128
// scratch aliased into A ends exactly at global row 2366 (float 2422784)
#define SCRATCH_ROWS 2366
#define FILL_SPLIT 7009   // (16384-2366)/2 rows filled by k_mid, rest by k_pair

typedef __attribute__((ext_vector_type(8))) short bf16x8;
typedef __attribute__((ext_vector_type(4))) float f32x4;

__constant__ int c_du[12] = {1,-1,0,0,2,-2,0,0,1, 1,-1,-1};
__constant__ int c_dv[12] = {0, 0,1,-1,0, 0,2,-2,1,-1, 1,-1};
__constant__ signed char c_rk[25] = {
  -1,-1, 5,-1,-1,
  -1,11, 1,10,-1,
   7, 3,-1, 2, 6,
  -1, 9, 0, 8,-1,
  -1,-1, 4,-1,-1};

__device__ inline ushort f2bf(float x) {
  unsigned u = __float_as_uint(x);
  u += 0x7FFF + ((u >> 16) & 1);
  return (ushort)(u >> 16);
}
__device__ inline float bf2f(ushort h) { return __uint_as_float(((unsigned)h) << 16); }

// write one identity row of A (zeros + diag); row given by global row index r_g
__device__ inline void identity_row(float* __restrict__ A, int r_g, int t) {
  int row = r_g & 1023;
  float4 o = make_float4(0.f, 0.f, 0.f, 0.f);
  if ((row >> 2) == t) {
    float dv = 1.0f / (1.0f + 1e-8f);
    int e = row & 3;
    if (e == 0) o.x = dv; else if (e == 1) o.y = dv;
    else if (e == 2) o.z = dv; else o.w = dv;
  }
  reinterpret_cast<float4*>(A + (size_t)r_g * 1024)[t] = o;
}
__device__ inline bool row_sampled(int row) {
  return ((row | (row >> 5)) & 1) == 0;   // pi=row>>5, pj=row&31 both even
}

// ============ k_pre: pool(6144) | EH(512) | transpose(208) ============
__global__ void __launch_bounds__(256) k_pre(const float* __restrict__ feat,
    const float* __restrict__ cemb, const float* __restrict__ W1,
    const float* __restrict__ b1, const float* __restrict__ W2,
    float* __restrict__ fg, ushort* __restrict__ g16,
    float* __restrict__ EH, ushort* __restrict__ WT16, ushort* __restrict__ W2T16) {
  __shared__ __align__(16) float sm[64 * 65];
  int blk = blockIdx.x;
  int t = threadIdx.x;
  if (blk < 6144) {
    // ---- pool ----
    int row = blk;
    const float4 v = reinterpret_cast<const float4*>(feat + (size_t)row * HWN)[t];
    float s = v.x + v.y + v.z + v.w;
#pragma unroll
    for (int m = 32; m >= 1; m >>= 1) s += __shfl_xor(s, m, 64);
    if ((t & 63) == 0) sm[t >> 6] = s;
    if ((t & 8) == 0) {
      int b = row / DD, d = row - b * DD;
      int u = t >> 4, r = t & 7;
      int s1 = u * 16 + 2 * r;
      g16[((size_t)(b * NS + s1)) * DD + d] = f2bf(v.x);
      g16[((size_t)(b * NS + s1 + 1)) * DD + d] = f2bf(v.z);
    }
    __syncthreads();
    if (t == 0) fg[row] = (sm[0] + sm[1] + sm[2] + sm[3]) * (1.0f / 1024.0f);
  } else if (blk < 6656) {
    // ---- EH ----
    int bs = blk - 6144;
    int c = bs >> 8, s = bs & 255;
    int u = s >> 4, v = s & 15;
    int pix = (u << 6) + (v << 1);
    float* ce = sm;
    if (t < 128) ce[t] = cemb[(size_t)pix * 128 + t];
    __syncthreads();
    const float* W = W1 + ((size_t)c * 1664 + 1536) * O1;
    float acc = 0.f;
    for (int e = 0; e < 128; e++) acc = fmaf(ce[e], W[(size_t)e * O1 + t], acc);
    EH[((size_t)(c * NS + s)) * O1 + t] = 0.5f * (acc + b1[c * O1 + t]);
  } else {
    // ---- transpose ----
    int r0 = blk - 6656;
    const float* src; ushort* dst; int K, N, k0, n0;
    if (r0 < 192) {
      int ch = r0 / 48, r = r0 % 48;
      int c = ch & 1, half = ch >> 1;
      src = W1 + ((size_t)c * 1664 + half * 768) * 256;
      dst = WT16 + (size_t)ch * 256 * 768;
      K = 768; N = 256; k0 = (r >> 2) * 64; n0 = (r & 3) * 64;
    } else {
      int r = r0 - 192;
      int c = r >> 3; int q = r & 7;
      src = W2 + (size_t)c * 256 * 128;
      dst = W2T16 + (size_t)c * 128 * 256;
      K = 256; N = 128; k0 = (q >> 1) * 64; n0 = (q & 1) * 64;
    }
    float (*T)[65] = reinterpret_cast<float(*)[65]>(sm);
    for (int i = 0; i < 16; i++) {
      int idx = i * 256 + t; int kl = idx >> 6, nl = idx & 63;
      T[kl][nl] = src[(size_t)(k0 + kl) * N + n0 + nl];
    }
    __syncthreads();
    for (int i = 0; i < 16; i++) {
      int idx = i * 256 + t; int nl = idx >> 6, kl = idx & 63;
      dst[(size_t)(n0 + nl) * K + k0 + kl] = f2bf(T[kl][nl]);
    }
  }
}

// ============ k_mid: gemm_mfma(512) | zpart(96) | A-identity fill ============
__global__ void __launch_bounds__(256) k_mid(const ushort* __restrict__ g16,
    const ushort* __restrict__ WT16, const float* __restrict__ EHb,
    const float* __restrict__ fg, const float* __restrict__ muW1,
    const float* __restrict__ lsW1,
    ushort* __restrict__ Fb16, float* __restrict__ zscr, float* __restrict__ A) {
  __shared__ __align__(16) float sm[4096];
  int blk = blockIdx.x;
  int t = threadIdx.x;
  if (blk >= 608) {
    // ---- identity fill, rows [SCRATCH_ROWS, SCRATCH_ROWS+FILL_SPLIT) ----
    int r_g = SCRATCH_ROWS + (blk - 608);
    if (!row_sampled(r_g & 1023)) identity_row(A, r_g, t);
    return;
  }
  if (blk < 512) {
    // ---- gemm_mfma ----
    int mt = blk & 31, nt = (blk >> 5) & 3, ch = blk >> 7;
    int c = ch & 1;
    int row0 = mt * 64, col0 = nt * 64;
    int wid = t >> 6, l = t & 63;
    int wm = wid & 1, wn = wid >> 1;
    int lm = l & 15, lk = (l >> 4) * 8;
    float (*ehs)[64] = reinterpret_cast<float(*)[64]>(sm);
    int s0 = row0 & 255;
    for (int i = 0; i < 16; i++) {
      int idx = i * 256 + t; int rl = idx >> 6, nl = idx & 63;
      ehs[rl][nl] = EHb[((size_t)(c * 256 + s0 + rl)) * 256 + col0 + nl];
    }
    f32x4 acc[2][2] = {};
    const ushort* ap0 = g16 + (size_t)(row0 + wm * 32 + lm) * DD + lk;
    const ushort* bp0 = WT16 + ((size_t)ch * 256 + col0 + wn * 32 + lm) * DD + lk;
#pragma unroll 4
    for (int k0 = 0; k0 < DD; k0 += 32) {
      bf16x8 a0 = *(const bf16x8*)(ap0 + k0);
      bf16x8 a1 = *(const bf16x8*)(ap0 + 16 * DD + k0);
      bf16x8 b0 = *(const bf16x8*)(bp0 + k0);
      bf16x8 b1 = *(const bf16x8*)(bp0 + 16 * DD + k0);
      acc[0][0] = __builtin_amdgcn_mfma_f32_16x16x32_bf16(a0, b0, acc[0][0], 0, 0, 0);
      acc[0][1] = __builtin_amdgcn_mfma_f32_16x16x32_bf16(a0, b1, acc[0][1], 0, 0, 0);
      acc[1][0] = __builtin_amdgcn_mfma_f32_16x16x32_bf16(a1, b0, acc[1][0], 0, 0, 0);
      acc[1][1] = __builtin_amdgcn_mfma_f32_16x16x32_bf16(a1, b1, acc[1][1], 0, 0, 0);
    }
    __syncthreads();
#pragma unroll
    for (int i = 0; i < 2; i++)
#pragma unroll
      for (int jj = 0; jj < 2; jj++)
#pragma unroll
        for (int r = 0; r < 4; r++) {
          int rm = wm * 32 + i * 16 + (l >> 4) * 4 + r;
          int cn = wn * 32 + jj * 16 + lm;
          float vo = acc[i][jj][r] + ehs[rm][cn];
          Fb16[((size_t)ch * 2048 + row0 + rm) * 256 + col0 + cn] = f2bf(vo);
        }
  } else {
    // ---- zpart ----
    int i = blk - 512;
    int chunk = i % 6, path = (i / 6) & 1, b = i / 12;
    int rg = t >> 6, ct = t & 63;
    float* sf = sm;
    float (*red)[256] = reinterpret_cast<float(*)[256]>(sm + 128);
    if (t < 128) sf[t] = fg[b * DD + chunk * 128 + t];
    __syncthreads();
    const float* W = (path ? lsW1 : muW1) + (size_t)(chunk * 128) * 256;
    float acc[4] = {0.f, 0.f, 0.f, 0.f};
#pragma unroll 4
    for (int it = 0; it < 32; it++) {
      int d = it * 4 + rg;
      float f = sf[d];
      float4 w = *reinterpret_cast<const float4*>(W + (size_t)d * 256 + ct * 4);
      acc[0] = fmaf(f, w.x, acc[0]);
      acc[1] = fmaf(f, w.y, acc[1]);
      acc[2] = fmaf(f, w.z, acc[2]);
      acc[3] = fmaf(f, w.w, acc[3]);
    }
    *reinterpret_cast<float4*>(&red[rg][ct * 4]) =
        make_float4(acc[0], acc[1], acc[2], acc[3]);
    __syncthreads();
    zscr[(((size_t)(b * 2 + path)) * 6 + chunk) * 256 + t] =
        red[0][t] + red[1][t] + red[2][t] + red[3][t];
  }
}

// ============ k_pair: pairmlp(768) | zfinish(8) | A-identity fill ============
__global__ void __launch_bounds__(256) k_pair(const ushort* __restrict__ Fb16,
    const ushort* __restrict__ W2T16, const float* __restrict__ b2,
    const float* __restrict__ W3, const float* __restrict__ b3,
    const float* __restrict__ zscr,
    const float* __restrict__ mub1, const float* __restrict__ muW2,
    const float* __restrict__ mub2,
    const float* __restrict__ lsb1, const float* __restrict__ lsW2,
    const float* __restrict__ lsb2, const float* __restrict__ eps,
    float* __restrict__ val,
    float* __restrict__ o_zmu, float* __restrict__ o_zls, float* __restrict__ o_zs,
    float* __restrict__ A) {
  __shared__ __align__(16) ushort h1s[64 * 256];
  __shared__ float psum2[2][64];
  int blk = blockIdx.x;
  int t = threadIdx.x;
  if (blk >= 776) {
    // ---- identity fill, rows [SCRATCH_ROWS+FILL_SPLIT, 16384) ----
    int r_g = SCRATCH_ROWS + FILL_SPLIT + (blk - 776);
    if (!row_sampled(r_g & 1023)) identity_row(A, r_g, t);
    return;
  }
  if (blk < 768) {
    // ---- pairmlp ----
    int bc = blk / 48, grp = blk - bc * 48;
    int b = bc >> 1, c = bc & 1;
    int wid = t >> 6, l = t & 63;
    int wm = wid & 1, wn = wid >> 1;
    int lm = l & 15, lk = (l >> 4) * 8;
    {
      int p_l = t >> 2, q = t & 3;
      int j = grp * 64 + p_l;
      int s = j / 12, ko = j - s * 12;
      int u = s >> 4, v = s & 15;
      int ub = u + c_du[ko], vb = v + c_dv[ko];
      bool vld = (ub >= 0) && (ub < 16) && (vb >= 0) && (vb < 16);
      int sb = vld ? ub * 16 + vb : s;
      const ushort* f1p = Fb16 + ((size_t)(c * 2048 + b * 256 + s)) * 256 + q * 64;
      const ushort* f2p = Fb16 + ((size_t)((2 + c) * 2048 + b * 256 + sb)) * 256 + q * 64;
      char* hb = (char*)h1s;
#pragma unroll
      for (int kk = 0; kk < 64; kk += 8) {
        bf16x8 x1 = *(const bf16x8*)(f1p + kk);
        bf16x8 x2 = *(const bf16x8*)(f2p + kk);
        bf16x8 o;
#pragma unroll
        for (int e = 0; e < 8; e++) {
          float a = bf2f((ushort)x1[e]) + bf2f((ushort)x2[e]);
          o[e] = (short)f2bf(fmaxf(a, 0.f));
        }
        int byt = (p_l * 512 + (q * 64 + kk) * 2) ^ ((p_l & 7) << 4);
        *(bf16x8*)(hb + byt) = o;
      }
    }
    __syncthreads();
    f32x4 acc[2][4] = {};
    const ushort* wp = W2T16 + ((size_t)(c * 128 + wn * 64 + lm)) * 256 + lk;
    const char* hb = (const char*)h1s;
    int p0 = wm * 32 + lm;
    int swz = (p0 & 7) << 4;
#pragma unroll 2
    for (int k0 = 0; k0 < 256; k0 += 32) {
      bf16x8 a0 = *(const bf16x8*)(hb + ((p0 * 512 + (k0 + lk) * 2) ^ swz));
      bf16x8 a1 = *(const bf16x8*)(hb + (((p0 + 16) * 512 + (k0 + lk) * 2) ^ swz));
#pragma unroll
      for (int nf = 0; nf < 4; nf++) {
        bf16x8 bb = *(const bf16x8*)(wp + nf * 16 * 256 + k0);
        acc[0][nf] = __builtin_amdgcn_mfma_f32_16x16x32_bf16(a0, bb, acc[0][nf], 0, 0, 0);
        acc[1][nf] = __builtin_amdgcn_mfma_f32_16x16x32_bf16(a1, bb, acc[1][nf], 0, 0, 0);
      }
    }
    float b2v[4], w3v[4];
#pragma unroll
    for (int nf = 0; nf < 4; nf++) {
      int col = wn * 64 + nf * 16 + lm;
      b2v[nf] = b2[c * 128 + col];
      w3v[nf] = W3[c * 128 + col];
    }
    float part[2][4];
#pragma unroll
    for (int mf = 0; mf < 2; mf++)
#pragma unroll
      for (int r = 0; r < 4; r++) {
        float ssum = 0.f;
#pragma unroll
        for (int nf = 0; nf < 4; nf++) {
          float h = fmaxf(acc[mf][nf][r] + b2v[nf], 0.f);
          ssum = fmaf(h, w3v[nf], ssum);
        }
        part[mf][r] = ssum;
      }
#pragma unroll
    for (int m = 1; m <= 8; m <<= 1)
#pragma unroll
      for (int mf = 0; mf < 2; mf++)
#pragma unroll
        for (int r = 0; r < 4; r++)
          part[mf][r] += __shfl_xor(part[mf][r], m, 64);
    if (lm == 0) {
#pragma unroll
      for (int mf = 0; mf < 2; mf++)
#pragma unroll
        for (int r = 0; r < 4; r++)
          psum2[wn][wm * 32 + mf * 16 + (l >> 4) * 4 + r] = part[mf][r];
    }
    __syncthreads();
    if (t < 64) {
      int jj = grp * 64 + t;
      int ss = jj / 12, kk2 = jj - ss * 12;
      int uu = ss >> 4, vv2 = ss & 15;
      int ub2 = uu + c_du[kk2], vb2 = vv2 + c_dv[kk2];
      bool vld = (ub2 >= 0) && (ub2 < 16) && (vb2 >= 0) && (vb2 < 16);
      float lg = psum2[0][t] + psum2[1][t] + b3[c];
      float sv = 1.0f / (1.0f + expf(-lg));
      val[(size_t)bc * PPAD + jj] = vld ? sv : 0.0f;
    }
  } else {
    // ---- zfinish ----
    int b = blk - 768;
    float* shm = (float*)h1s;
    float* shl = shm + 256;
    float* zres = shm + 512;
    float hm = mub1[t], hl = lsb1[t];
#pragma unroll
    for (int ch = 0; ch < 6; ch++) {
      hm += zscr[(((size_t)(b * 2 + 0)) * 6 + ch) * 256 + t];
      hl += zscr[(((size_t)(b * 2 + 1)) * 6 + ch) * 256 + t];
    }
    shm[t] = fmaxf(hm, 0.f);
    shl[t] = fmaxf(hl, 0.f);
    __syncthreads();
    if (t < 128 && (t & 63) < 8) {
      int path = t >> 6, kk = t & 7;
      const float* W2p = path ? lsW2 : muW2;
      const float* bi = path ? lsb2 : mub2;
      const float* sh = path ? shl : shm;
      float z = bi[kk];
      for (int i = 0; i < 256; i++) z = fmaf(sh[i], W2p[i * 8 + kk], z);
      zres[path * 8 + kk] = z;
    }
    __syncthreads();
    if (t < 8) {
      float zm = zres[t], zl = zres[8 + t];
      o_zmu[b * 8 + t] = zm;
      o_zls[b * 8 + t] = zl;
      o_zs[b * 8 + t] = zm + expf(zl) * eps[b * 8 + t];
    }
  }
}

// ============ k_final: sampled rows(4096) | early rows(2366) | diffuse(16) ============
__global__ void __launch_bounds__(256) k_final(const float* __restrict__ val,
    const float* __restrict__ cam,
    const float* __restrict__ csc, const float* __restrict__ cbi,
    float* __restrict__ A, float* __restrict__ o_cam, float* __restrict__ o_conf) {
  __shared__ float smf[260];
  int blk = blockIdx.x;
  int t = threadIdx.x;
  if (blk < 4096) {
    // ---- sampled-site rows ----
    int bc = blk >> 8, s = blk & 255;
    int u = s >> 4, v = s & 15;
    int row = u * 64 + 2 * v;
    size_t base = (size_t)bc * HWN * HWN + (size_t)row * HWN;
    float* sv = smf;
    if (t < 12) sv[t] = val[(size_t)bc * PPAD + s * 12 + t];
    __syncthreads();
    if (t == 0) {
      float ssum = 1.f;
      for (int k = 0; k < 12; k++) ssum += sv[k];
      smf[12] = 1.f / (ssum + 1e-8f);
    }
    __syncthreads();
    float inv = smf[12];
    float vo[4];
#pragma unroll
    for (int e = 0; e < 4; e++) {
      int col = t * 4 + e;
      float x = 0.f;
      if (col == row) {
        x = inv;
      } else if ((col & 33) == 0) {
        int cu = col >> 6, cv = (col & 31) >> 1;
        int du = cu - u + 2, dv = cv - v + 2;
        if (((unsigned)du < 5u) && ((unsigned)dv < 5u)) {
          int k = c_rk[du * 5 + dv];
          if (k >= 0) x = sv[k] * inv;
        }
      }
      vo[e] = x;
    }
    reinterpret_cast<float4*>(A + base)[t] =
        make_float4(vo[0], vo[1], vo[2], vo[3]);
  } else if (blk < 4096 + SCRATCH_ROWS) {
    // ---- early rows (former scratch region): identity for non-sampled ----
    int r_g = blk - 4096;
    if (!row_sampled(r_g & 1023)) identity_row(A, r_g, t);
  } else {
    // ---- diffuse ----
    int bc = blk - (4096 + SCRATCH_ROWS);
    float* M = smf;
    int u = t >> 4, v = t & 15;
    int pix = (u << 6) + (v << 1);
    const float* camr = cam + (size_t)bc * HWN;
    float m = camr[pix];
    float vv[12];
    int nb[12];
    float ssum = 1.f;
#pragma unroll
    for (int k = 0; k < 12; k++) {
      int ub = u + c_du[k], vb = v + c_dv[k];
      bool vld = (ub >= 0) && (ub < 16) && (vb >= 0) && (vb < 16);
      nb[k] = vld ? ub * 16 + vb : t;
      vv[k] = vld ? val[(size_t)bc * PPAD + t * 12 + k] : 0.0f;
      ssum += vv[k];
    }
    float inv = 1.0f / (ssum + 1e-8f);
    float degn = ssum * inv;
    M[t] = m;
    __syncthreads();
    for (int step = 0; step < 3; step++) {
      float accv = m;
#pragma unroll
      for (int k = 0; k < 12; k++) accv = fmaf(vv[k], M[nb[k]], accv);
      float L = accv * inv - degn * m;
      m = fmaf(0.1f, L, m);
      __syncthreads();
      M[t] = m;
      __syncthreads();
    }
    float scale = csc[0], bias = cbi[0];
    for (int p = t; p < HWN; p += 256) {
      int ppi = p >> 5, ppj = p & 31;
      float x;
      if (((ppi | ppj) & 1) == 0) x = M[(ppi >> 1) * 16 + (ppj >> 1)];
      else x = camr[p];
      x = fminf(fmaxf(x, 0.0f), 1.0f);
      o_cam[(size_t)bc * HWN + p] = x;
      o_conf[(size_t)bc * HWN + p] = 1.0f / (1.0f + expf(-(scale * x + bias)));
    }
  }
}

extern "C" void kernel_launch(void* const* d_in, const int* in_sizes, int n_in,
                              void* d_out, int out_size, void* d_ws, size_t ws_size,
                              hipStream_t stream) {
  const float* feat = (const float*)d_in[0];
  const float* cam  = (const float*)d_in[1];
  const float* eps  = (const float*)d_in[3];
  const float* cemb = (const float*)d_in[4];
  const float* aW1  = (const float*)d_in[5];
  const float* ab1  = (const float*)d_in[6];
  const float* aW2  = (const float*)d_in[7];
  const float* ab2  = (const float*)d_in[8];
  const float* aW3  = (const float*)d_in[9];
  const float* ab3  = (const float*)d_in[10];
  const float* muW1 = (const float*)d_in[11];
  const float* mub1 = (const float*)d_in[12];
  const float* muW2 = (const float*)d_in[13];
  const float* mub2 = (const float*)d_in[14];
  const float* lsW1 = (const float*)d_in[15];
  const float* lsb1 = (const float*)d_in[16];
  const float* lsW2 = (const float*)d_in[17];
  const float* lsb2 = (const float*)d_in[18];
  const float* csc  = (const float*)d_in[19];
  const float* cbi  = (const float*)d_in[20];

  float* out = (float*)d_out;
  float* o_cam  = out;                       // 16384
  float* o_zmu  = out + 16384;               // 64
  float* o_zls  = out + 16448;               // 64
  float* o_zs   = out + 16512;               // 64
  float* o_A    = out + 16576;               // 16777216
  float* o_conf = out + 16793792;            // 16384

  // scratch aliased into the A region (rows < 2366); only val in d_ws
  float*  fg    = o_A;                                   // 6144 f32
  float*  EHb   = o_A + 6144;                            // 131072 f32
  ushort* g16   = (ushort*)(o_A + 137216);               // 2048*768 bf16
  ushort* WT16  = (ushort*)(o_A + 923648);               // 4*256*768 bf16
  ushort* W2T16 = (ushort*)(o_A + 1316864);              // 2*128*256 bf16
  ushort* Fb16  = (ushort*)(o_A + 1349632);              // 4*2048*256 bf16
  float*  zscr  = o_A + 2398208;                         // ends @2422784 = row 2366
  float*  valb  = (float*)d_ws;                          // 16*3072 f32

  hipLaunchKernelGGL(k_pre, dim3(6864), dim3(256), 0, stream,
                     feat, cemb, aW1, ab1, aW2, fg, g16, EHb, WT16, W2T16);
  hipLaunchKernelGGL(k_mid, dim3(608 + FILL_SPLIT), dim3(256), 0, stream,
                     g16, WT16, EHb, fg, muW1, lsW1, Fb16, zscr, o_A);
  hipLaunchKernelGGL(k_pair, dim3(776 + (16384 - SCRATCH_ROWS - FILL_SPLIT)),
                     dim3(256), 0, stream,
                     Fb16, W2T16, ab2, aW3, ab3, zscr,
                     mub1, muW2, mub2, lsb1, lsW2, lsb2, eps,
                     valb, o_zmu, o_zls, o_zs, o_A);
  hipLaunchKernelGGL(k_final, dim3(4096 + SCRATCH_ROWS + 16), dim3(256), 0, stream,
                     valb, cam, csc, cbi, o_A, o_cam, o_conf);
}